// Round 1
// baseline (176.554 us; speedup 1.0000x reference)
//
#include <hip/hip_runtime.h>
#include <hip/hip_bf16.h>

typedef unsigned short u16;
typedef __attribute__((ext_vector_type(8))) short short8;
typedef __attribute__((ext_vector_type(4))) float float4v;

#define N_ROWS 4096
#define DIM    1024
#define MARGIN 0.5f

// ---------------- helpers ----------------

__device__ __forceinline__ float wave_reduce(float v) {
    #pragma unroll
    for (int off = 32; off > 0; off >>= 1) v += __shfl_xor(v, off, 64);
    return v;
}

__device__ __forceinline__ u16 f2bf(float x) {
    __hip_bfloat16 h = __float2bfloat16(x);
    return *(u16*)&h;
}

__device__ __forceinline__ void gl_lds16(const void* g, void* l) {
    __builtin_amdgcn_global_load_lds(
        (const __attribute__((address_space(1))) void*)g,
        (__attribute__((address_space(3))) void*)l,
        16, 0, 0);
}

// ---------------- kernel 1: norms + positive term + bf16 pre-normalized copies ----------------
// One block per row. 256 threads, 4 fp32 elems each (D=1024).

__global__ __launch_bounds__(256) void rowprep(
        const float* __restrict__ img, const float* __restrict__ txt,
        u16* __restrict__ imgn, u16* __restrict__ txtn,
        float* __restrict__ out) {
    const int row = blockIdx.x;
    const int t = threadIdx.x;
    const int wave = t >> 6, lane = t & 63;

    const float4* ip = (const float4*)(img + (size_t)row * DIM);
    const float4* tp = (const float4*)(txt + (size_t)row * DIM);
    float4 iv = ip[t];
    float4 tv = tp[t];

    float sii = iv.x*tv.x + iv.y*tv.y + iv.z*tv.z + iv.w*tv.w;
    float si2 = iv.x*iv.x + iv.y*iv.y + iv.z*iv.z + iv.w*iv.w;
    float st2 = tv.x*tv.x + tv.y*tv.y + tv.z*tv.z + tv.w*tv.w;

    sii = wave_reduce(sii);
    si2 = wave_reduce(si2);
    st2 = wave_reduce(st2);

    __shared__ float red[3][4];
    __shared__ float invs[2];
    if (lane == 0) { red[0][wave] = sii; red[1][wave] = si2; red[2][wave] = st2; }
    __syncthreads();
    if (t == 0) {
        float a = red[0][0] + red[0][1] + red[0][2] + red[0][3];
        float b = red[1][0] + red[1][1] + red[1][2] + red[1][3];
        float c = red[2][0] + red[2][1] + red[2][2] + red[2][3];
        float ni = fmaxf(sqrtf(b), 1e-8f);
        float nt = fmaxf(sqrtf(c), 1e-8f);
        float pos = a / (ni * nt);
        float d = 1.0f - pos;
        atomicAdd(out, d * d * (1.0f / (float)N_ROWS));
        invs[0] = 1.0f / ni;
        invs[1] = 1.0f / nt;
    }
    __syncthreads();
    float ii = invs[0], it = invs[1];

    ushort4 oi, ot;
    oi.x = f2bf(iv.x * ii); oi.y = f2bf(iv.y * ii); oi.z = f2bf(iv.z * ii); oi.w = f2bf(iv.w * ii);
    ot.x = f2bf(tv.x * it); ot.y = f2bf(tv.y * it); ot.z = f2bf(tv.z * it); ot.w = f2bf(tv.w * it);
    ((ushort4*)(imgn + (size_t)row * DIM))[t] = oi;
    ((ushort4*)(txtn + (size_t)row * DIM))[t] = ot;
}

// ---------------- kernel 2: pairwise cosine GEMM + fused hinge reduction ----------------
// A (imgn) and B (txtn) are row-major [4096][1024] bf16, pre-normalized.
// C[i][j] = sum_k A[i,k] * B[j,k].  Contribution: (i != j) * relu(C - 0.5)^2.
// m97 structure: 128x128 block tile, BK=32, 256 threads = 4 waves (2x2),
// each wave 64x64 = 4x4 tiles of 16x16x32 MFMA. global_load_lds width=16.

#define BM 128
#define BN 128
#define BK 32

__global__ __launch_bounds__(256) void negloss(
        const u16* __restrict__ A, const u16* __restrict__ B,
        float* __restrict__ out) {
    __shared__ __align__(16) u16 sA[BM * BK];
    __shared__ __align__(16) u16 sB[BN * BK];

    const int tid = threadIdx.x;
    const int wave = tid >> 6, lane = tid & 63;
    const int wr = wave >> 1, wc = wave & 1;
    const int rA0 = blockIdx.y * BM;
    const int rB0 = blockIdx.x * BN;

    float4v acc[4][4] = {};

    const int mrow = lane & 15;         // fragment row within 16
    const int kq = (lane >> 4) * 8;     // fragment k-offset (quad*8)

    for (int k0 = 0; k0 < DIM; k0 += BK) {
        __syncthreads();   // previous iter's LDS reads done before overwrite
        #pragma unroll
        for (int r = 0; r < 2; ++r) {
            // uniform (per-wave) byte offset within the 8 KiB tile; HW adds lane*16
            int uoff = r * 4096 + wave * 1024;
            int o = uoff + lane * 16;            // this lane's byte offset in tile
            int row = o >> 6;                    // 64 B per tile row (32 bf16)
            int colb = o & 63;
            const char* gA = (const char*)A + ((size_t)(rA0 + row) * DIM + k0) * 2 + colb;
            const char* gB = (const char*)B + ((size_t)(rB0 + row) * DIM + k0) * 2 + colb;
            gl_lds16(gA, (char*)sA + uoff);
            gl_lds16(gB, (char*)sB + uoff);
        }
        __syncthreads();   // drains vmcnt before LDS reads

        short8 af[4], bf[4];
        #pragma unroll
        for (int i = 0; i < 4; ++i) {
            af[i] = *(const short8*)&sA[(wr * 64 + i * 16 + mrow) * BK + kq];
            bf[i] = *(const short8*)&sB[(wc * 64 + i * 16 + mrow) * BK + kq];
        }
        #pragma unroll
        for (int i = 0; i < 4; ++i)
            #pragma unroll
            for (int j = 0; j < 4; ++j)
                acc[i][j] = __builtin_amdgcn_mfma_f32_16x16x32_bf16(af[i], bf[j], acc[i][j], 0, 0, 0);
    }

    // epilogue: C/D layout col=lane&15, row=(lane>>4)*4+reg
    float local = 0.0f;
    const int crow = (lane >> 4) * 4;
    const int ccol = lane & 15;
    #pragma unroll
    for (int i = 0; i < 4; ++i) {
        int gi_base = rA0 + wr * 64 + i * 16 + crow;
        #pragma unroll
        for (int j = 0; j < 4; ++j) {
            int gj = rB0 + wc * 64 + j * 16 + ccol;
            #pragma unroll
            for (int r = 0; r < 4; ++r) {
                float v = acc[i][j][r];
                float h = fmaxf(v - MARGIN, 0.0f);
                if (gi_base + r == gj) h = 0.0f;   // diagonal zeroed
                local += h * h;
            }
        }
    }

    local = wave_reduce(local);
    __shared__ float part[4];
    if (lane == 0) part[wave] = local;
    __syncthreads();
    if (tid == 0) {
        float s = part[0] + part[1] + part[2] + part[3];
        atomicAdd(out, s * (1.0f / ((float)N_ROWS * (float)N_ROWS)));
    }
}

// ---------------- launch ----------------

extern "C" void kernel_launch(void* const* d_in, const int* in_sizes, int n_in,
                              void* d_out, int out_size, void* d_ws, size_t ws_size,
                              hipStream_t stream) {
    const float* img = (const float*)d_in[0];
    const float* txt = (const float*)d_in[1];
    float* out = (float*)d_out;

    u16* imgn = (u16*)d_ws;
    u16* txtn = imgn + (size_t)N_ROWS * DIM;

    hipMemsetAsync(d_out, 0, sizeof(float), stream);
    rowprep<<<N_ROWS, 256, 0, stream>>>(img, txt, imgn, txtn, out);
    negloss<<<dim3(N_ROWS / BN, N_ROWS / BM), 256, 0, stream>>>(imgn, txtn, out);
}

// Round 2
// 123.767 us; speedup vs baseline: 1.4265x; 1.4265x over previous
//
#include <hip/hip_runtime.h>
#include <hip/hip_bf16.h>

typedef unsigned short u16;
typedef __attribute__((ext_vector_type(8))) short short8;
typedef __attribute__((ext_vector_type(4))) float float4v;

#define N_ROWS 4096
#define DIM    1024
#define MARGIN 0.5f

// ---------------- helpers ----------------

__device__ __forceinline__ float wave_reduce(float v) {
    #pragma unroll
    for (int off = 32; off > 0; off >>= 1) v += __shfl_xor(v, off, 64);
    return v;   // butterfly: ALL lanes hold the sum
}

__device__ __forceinline__ u16 f2bf(float x) {
    __hip_bfloat16 h = __float2bfloat16(x);
    return *(u16*)&h;
}

__device__ __forceinline__ void gl_lds16(const void* g, void* l) {
    __builtin_amdgcn_global_load_lds(
        (const __attribute__((address_space(1))) void*)g,
        (__attribute__((address_space(3))) void*)l,
        16, 0, 0);
}

// ---------------- kernel 1: norms + positive term + bf16 pre-normalized copies ----------------
// One row per WAVE (no block barriers in hot path). 1024 blocks x 256 thr = 4096 waves.
// Lane loads 16 fp32 per input (4x float4, stride-64 float4 pattern = coalesced).

__global__ __launch_bounds__(256) void rowprep(
        const float* __restrict__ img, const float* __restrict__ txt,
        u16* __restrict__ imgn, u16* __restrict__ txtn,
        float* __restrict__ pospart) {
    const int t = threadIdx.x;
    const int wave = t >> 6, lane = t & 63;
    const int row = blockIdx.x * 4 + wave;

    const float4* ip = (const float4*)(img + (size_t)row * DIM);
    const float4* tp = (const float4*)(txt + (size_t)row * DIM);

    float4 iv[4], tv[4];
    #pragma unroll
    for (int k = 0; k < 4; ++k) {
        iv[k] = ip[k * 64 + lane];
        tv[k] = tp[k * 64 + lane];
    }

    float sii = 0.f, si2 = 0.f, st2 = 0.f;
    #pragma unroll
    for (int k = 0; k < 4; ++k) {
        sii += iv[k].x*tv[k].x + iv[k].y*tv[k].y + iv[k].z*tv[k].z + iv[k].w*tv[k].w;
        si2 += iv[k].x*iv[k].x + iv[k].y*iv[k].y + iv[k].z*iv[k].z + iv[k].w*iv[k].w;
        st2 += tv[k].x*tv[k].x + tv[k].y*tv[k].y + tv[k].z*tv[k].z + tv[k].w*tv[k].w;
    }

    sii = wave_reduce(sii);
    si2 = wave_reduce(si2);
    st2 = wave_reduce(st2);

    float ni = fmaxf(sqrtf(si2), 1e-8f);
    float nt = fmaxf(sqrtf(st2), 1e-8f);
    float ii = 1.0f / ni, it = 1.0f / nt;

    // bf16 pre-normalized writes (ushort4 = 8 B/lane per chunk, coalesced)
    ushort4* oi = (ushort4*)(imgn + (size_t)row * DIM);
    ushort4* ot = (ushort4*)(txtn + (size_t)row * DIM);
    #pragma unroll
    for (int k = 0; k < 4; ++k) {
        ushort4 a, b;
        a.x = f2bf(iv[k].x * ii); a.y = f2bf(iv[k].y * ii);
        a.z = f2bf(iv[k].z * ii); a.w = f2bf(iv[k].w * ii);
        b.x = f2bf(tv[k].x * it); b.y = f2bf(tv[k].y * it);
        b.z = f2bf(tv[k].z * it); b.w = f2bf(tv[k].w * it);
        oi[k * 64 + lane] = a;
        ot[k * 64 + lane] = b;
    }

    // positive-loss partial: one value per wave -> LDS -> one store per block
    float d = 1.0f - sii * ii * it;
    float p = d * d;
    __shared__ float red[4];
    if (lane == 0) red[wave] = p;
    __syncthreads();
    if (t == 0)
        pospart[blockIdx.x] = red[0] + red[1] + red[2] + red[3];
}

// ---------------- kernel 2: pairwise cosine GEMM + fused hinge reduction ----------------
// A (imgn), B (txtn): row-major [4096][1024] bf16, pre-normalized.
// C[i][j] = sum_k A[i,k]*B[j,k]; contribution (i!=j)*relu(C-0.5)^2.
// m97 structure: 128x128 tile, BK=32, 4 waves (2x2), 4x4 16x16x32 MFMA per wave,
// global_load_lds width=16 staging.

#define BM 128
#define BN 128
#define BK 32

__global__ __launch_bounds__(256) void negloss(
        const u16* __restrict__ A, const u16* __restrict__ B,
        float* __restrict__ negpart) {
    __shared__ __align__(16) u16 sA[BM * BK];
    __shared__ __align__(16) u16 sB[BN * BK];

    const int tid = threadIdx.x;
    const int wave = tid >> 6, lane = tid & 63;
    const int wr = wave >> 1, wc = wave & 1;
    const int rA0 = blockIdx.y * BM;
    const int rB0 = blockIdx.x * BN;

    float4v acc[4][4] = {};

    const int mrow = lane & 15;
    const int kq = (lane >> 4) * 8;

    for (int k0 = 0; k0 < DIM; k0 += BK) {
        __syncthreads();
        #pragma unroll
        for (int r = 0; r < 2; ++r) {
            int uoff = r * 4096 + wave * 1024;   // wave-uniform byte offset in tile
            int o = uoff + lane * 16;
            int row = o >> 6;                    // 64 B per tile row (32 bf16)
            int colb = o & 63;
            const char* gA = (const char*)A + ((size_t)(rA0 + row) * DIM + k0) * 2 + colb;
            const char* gB = (const char*)B + ((size_t)(rB0 + row) * DIM + k0) * 2 + colb;
            gl_lds16(gA, (char*)sA + uoff);
            gl_lds16(gB, (char*)sB + uoff);
        }
        __syncthreads();

        short8 af[4], bf[4];
        #pragma unroll
        for (int i = 0; i < 4; ++i) {
            af[i] = *(const short8*)&sA[(wr * 64 + i * 16 + mrow) * BK + kq];
            bf[i] = *(const short8*)&sB[(wc * 64 + i * 16 + mrow) * BK + kq];
        }
        #pragma unroll
        for (int i = 0; i < 4; ++i)
            #pragma unroll
            for (int j = 0; j < 4; ++j)
                acc[i][j] = __builtin_amdgcn_mfma_f32_16x16x32_bf16(af[i], bf[j], acc[i][j], 0, 0, 0);
    }

    // epilogue: C/D layout col=lane&15, row=(lane>>4)*4+reg
    float local = 0.0f;
    const int crow = (lane >> 4) * 4;
    const int ccol = lane & 15;
    #pragma unroll
    for (int i = 0; i < 4; ++i) {
        int gi_base = rA0 + wr * 64 + i * 16 + crow;
        #pragma unroll
        for (int j = 0; j < 4; ++j) {
            int gj = rB0 + wc * 64 + j * 16 + ccol;
            #pragma unroll
            for (int r = 0; r < 4; ++r) {
                float v = acc[i][j][r];
                float h = fmaxf(v - MARGIN, 0.0f);
                if (gi_base + r == gj) h = 0.0f;
                local += h * h;
            }
        }
    }

    local = wave_reduce(local);
    __shared__ float part[4];
    if (lane == 0) part[wave] = local;
    __syncthreads();
    if (tid == 0)
        negpart[blockIdx.y * gridDim.x + blockIdx.x] = part[0] + part[1] + part[2] + part[3];
}

// ---------------- kernel 3: final reduction ----------------

__global__ __launch_bounds__(256) void finalize(
        const float* __restrict__ pospart, const float* __restrict__ negpart,
        float* __restrict__ out) {
    const int t = threadIdx.x;
    const int wave = t >> 6, lane = t & 63;
    float sp = 0.f, sn = 0.f;
    #pragma unroll
    for (int i = 0; i < 4; ++i) {
        sp += pospart[i * 256 + t];
        sn += negpart[i * 256 + t];
    }
    sp = wave_reduce(sp);
    sn = wave_reduce(sn);
    __shared__ float rp[4], rn[4];
    if (lane == 0) { rp[wave] = sp; rn[wave] = sn; }
    __syncthreads();
    if (t == 0) {
        float pos = rp[0] + rp[1] + rp[2] + rp[3];
        float neg = rn[0] + rn[1] + rn[2] + rn[3];
        out[0] = pos * (1.0f / (float)N_ROWS)
               + neg * (1.0f / ((float)N_ROWS * (float)N_ROWS));
    }
}

// ---------------- launch ----------------

extern "C" void kernel_launch(void* const* d_in, const int* in_sizes, int n_in,
                              void* d_out, int out_size, void* d_ws, size_t ws_size,
                              hipStream_t stream) {
    const float* img = (const float*)d_in[0];
    const float* txt = (const float*)d_in[1];
    float* out = (float*)d_out;

    u16* imgn = (u16*)d_ws;                                   // 8 MiB
    u16* txtn = imgn + (size_t)N_ROWS * DIM;                  // 8 MiB
    float* pospart = (float*)(txtn + (size_t)N_ROWS * DIM);   // 4 KiB
    float* negpart = pospart + 1024;                          // 4 KiB

    rowprep<<<N_ROWS / 4, 256, 0, stream>>>(img, txt, imgn, txtn, pospart);
    negloss<<<dim3(N_ROWS / BN, N_ROWS / BM), 256, 0, stream>>>(imgn, txtn, negpart);
    finalize<<<1, 256, 0, stream>>>(pospart, negpart, out);
}

// Round 3
// 98.119 us; speedup vs baseline: 1.7994x; 1.2614x over previous
//
#include <hip/hip_runtime.h>
#include <hip/hip_bf16.h>

typedef unsigned char  u8;
typedef unsigned short u16;
typedef __attribute__((ext_vector_type(4))) int   int4v;
typedef __attribute__((ext_vector_type(8))) int   int8v;
typedef __attribute__((ext_vector_type(4))) float float4v;

#define N_ROWS 4096
#define DIM    1024
#define MARGIN 0.5f
#define FP8_SCALE 32.0f          // pre-scale folded into fp8 quantization
#define INV_SCALE2 (1.0f / (FP8_SCALE * FP8_SCALE))

// ---------------- helpers ----------------

__device__ __forceinline__ float wave_reduce(float v) {
    #pragma unroll
    for (int off = 32; off > 0; off >>= 1) v += __shfl_xor(v, off, 64);
    return v;   // butterfly: ALL lanes hold the sum
}

__device__ __forceinline__ void gl_lds16(const void* g, void* l) {
    __builtin_amdgcn_global_load_lds(
        (const __attribute__((address_space(1))) void*)g,
        (__attribute__((address_space(3))) void*)l,
        16, 0, 0);
}

// ---------------- kernel 1: norms + positive term + fp8 pre-normalized copies ----------------
// One row per WAVE. 1024 blocks x 256 thr. Lane loads 16 fp32 per input,
// writes 16 fp8 (x * 32/||x||) as 4 dword stores.

__global__ __launch_bounds__(256) void rowprep(
        const float* __restrict__ img, const float* __restrict__ txt,
        u8* __restrict__ imgn, u8* __restrict__ txtn,
        float* __restrict__ pospart) {
    const int t = threadIdx.x;
    const int wave = t >> 6, lane = t & 63;
    const int row = blockIdx.x * 4 + wave;

    const float4* ip = (const float4*)(img + (size_t)row * DIM);
    const float4* tp = (const float4*)(txt + (size_t)row * DIM);

    float4 iv[4], tv[4];
    #pragma unroll
    for (int k = 0; k < 4; ++k) {
        iv[k] = ip[k * 64 + lane];
        tv[k] = tp[k * 64 + lane];
    }

    float sii = 0.f, si2 = 0.f, st2 = 0.f;
    #pragma unroll
    for (int k = 0; k < 4; ++k) {
        sii += iv[k].x*tv[k].x + iv[k].y*tv[k].y + iv[k].z*tv[k].z + iv[k].w*tv[k].w;
        si2 += iv[k].x*iv[k].x + iv[k].y*iv[k].y + iv[k].z*iv[k].z + iv[k].w*iv[k].w;
        st2 += tv[k].x*tv[k].x + tv[k].y*tv[k].y + tv[k].z*tv[k].z + tv[k].w*tv[k].w;
    }

    sii = wave_reduce(sii);
    si2 = wave_reduce(si2);
    st2 = wave_reduce(st2);

    float ni = fmaxf(sqrtf(si2), 1e-8f);
    float nt = fmaxf(sqrtf(st2), 1e-8f);
    float ii = 1.0f / ni, it = 1.0f / nt;
    float si = FP8_SCALE * ii, st = FP8_SCALE * it;

    // fp8 conversion (OCP e4m3 on gfx950), 4B per chunk, coalesced dword stores
    unsigned int* oi = (unsigned int*)(imgn + (size_t)row * DIM);
    unsigned int* ot = (unsigned int*)(txtn + (size_t)row * DIM);
    #pragma unroll
    for (int k = 0; k < 4; ++k) {
        int pa = __builtin_amdgcn_cvt_pk_fp8_f32(iv[k].x * si, iv[k].y * si, 0, 0);
        pa     = __builtin_amdgcn_cvt_pk_fp8_f32(iv[k].z * si, iv[k].w * si, pa, 1);
        int pb = __builtin_amdgcn_cvt_pk_fp8_f32(tv[k].x * st, tv[k].y * st, 0, 0);
        pb     = __builtin_amdgcn_cvt_pk_fp8_f32(tv[k].z * st, tv[k].w * st, pb, 1);
        oi[k * 64 + lane] = (unsigned int)pa;
        ot[k * 64 + lane] = (unsigned int)pb;
    }

    float d = 1.0f - sii * ii * it;
    float p = d * d;
    __shared__ float red[4];
    if (lane == 0) red[wave] = p;
    __syncthreads();
    if (t == 0)
        pospart[blockIdx.x] = red[0] + red[1] + red[2] + red[3];
}

// ---------------- kernel 2: pairwise cosine GEMM (MX-fp8 K=128) + fused hinge ----------------
// A (imgn), B (txtn): row-major [4096][1024] fp8 e4m3, pre-normalized * 32.
// C[i][j] = sum_k A[i,k]*B[j,k] = 1024 * sim.  Contribution (i!=j)*relu(sim-0.5)^2.
// 128x128 block tile, BK=128 bytes, 4 waves (2x2), each wave 4x4 of 16x16x128
// scaled-MFMA (scales = 1.0). LDS tiles XOR-swizzled at 16B-chunk granularity:
// physical_chunk = logical_chunk ^ (row & 7)  -> conflict-free ds_read_b128.

#define BM 128
#define BN 128

__global__ __launch_bounds__(256) void negloss(
        const u8* __restrict__ A, const u8* __restrict__ B,
        float* __restrict__ negpart) {
    __shared__ __align__(16) u8 sA[BM * 128];   // 16 KiB
    __shared__ __align__(16) u8 sB[BN * 128];   // 16 KiB

    const int tid = threadIdx.x;
    const int wave = tid >> 6, lane = tid & 63;
    const int wr = wave >> 1, wc = wave & 1;
    const int rA0 = blockIdx.y * BM;
    const int rB0 = blockIdx.x * BN;

    const int mrow = lane & 15;     // fragment row within 16
    const int kg = lane >> 4;       // k-group: lane holds logical bytes [kg*32, kg*32+32)

    float4v acc[4][4] = {};

    for (int it = 0; it < DIM / 128; ++it) {
        const int k0 = it * 128;
        __syncthreads();            // prior iter's LDS reads done
        #pragma unroll
        for (int r = 0; r < 4; ++r) {
            int uoff = r * 4096 + wave * 1024;     // wave-uniform dest in tile
            int o = uoff + lane * 16;
            int row = o >> 7;                      // 128 B per tile row
            int lc = ((o >> 4) & 7) ^ (row & 7);   // inverse swizzle on global src
            const char* gA = (const char*)A + (size_t)(rA0 + row) * DIM + k0 + lc * 16;
            const char* gB = (const char*)B + (size_t)(rB0 + row) * DIM + k0 + lc * 16;
            gl_lds16(gA, (char*)sA + uoff);
            gl_lds16(gB, (char*)sB + uoff);
        }
        __syncthreads();            // staging visible

        int8v af[4], bf[4];
        #pragma unroll
        for (int i = 0; i < 4; ++i) {
            int ra = wr * 64 + i * 16 + mrow;
            int ca = (2 * kg) ^ (ra & 7);
            int4v lo = *(const int4v*)(sA + ra * 128 + ca * 16);
            int4v hi = *(const int4v*)(sA + ra * 128 + (ca ^ 1) * 16);
            int rb = wc * 64 + i * 16 + mrow;
            int cb = (2 * kg) ^ (rb & 7);
            int4v blo = *(const int4v*)(sB + rb * 128 + cb * 16);
            int4v bhi = *(const int4v*)(sB + rb * 128 + (cb ^ 1) * 16);
            #pragma unroll
            for (int q = 0; q < 4; ++q) {
                af[i][q] = lo[q]; af[i][q + 4] = hi[q];
                bf[i][q] = blo[q]; bf[i][q + 4] = bhi[q];
            }
        }
        #pragma unroll
        for (int i = 0; i < 4; ++i)
            #pragma unroll
            for (int j = 0; j < 4; ++j)
                acc[i][j] = __builtin_amdgcn_mfma_scale_f32_16x16x128_f8f6f4(
                    af[i], bf[j], acc[i][j],
                    0 /*A fmt: fp8 e4m3*/, 0 /*B fmt: fp8 e4m3*/,
                    0, 0x7F7F7F7F /*scale A = 1.0*/,
                    0, 0x7F7F7F7F /*scale B = 1.0*/);
    }

    // epilogue: C/D layout (16x16 shapes): col = lane&15, row = (lane>>4)*4 + reg
    float local = 0.0f;
    const int crow = (lane >> 4) * 4;
    const int ccol = lane & 15;
    #pragma unroll
    for (int i = 0; i < 4; ++i) {
        int gi_base = rA0 + wr * 64 + i * 16 + crow;
        #pragma unroll
        for (int j = 0; j < 4; ++j) {
            int gj = rB0 + wc * 64 + j * 16 + ccol;
            #pragma unroll
            for (int r = 0; r < 4; ++r) {
                float sim = acc[i][j][r] * INV_SCALE2;
                float h = fmaxf(sim - MARGIN, 0.0f);
                if (gi_base + r == gj) h = 0.0f;   // diagonal zeroed
                local += h * h;
            }
        }
    }

    local = wave_reduce(local);
    __shared__ float part[4];
    if (lane == 0) part[wave] = local;
    __syncthreads();
    if (tid == 0)
        negpart[blockIdx.y * gridDim.x + blockIdx.x] = part[0] + part[1] + part[2] + part[3];
}

// ---------------- kernel 3: final reduction ----------------

__global__ __launch_bounds__(256) void finalize(
        const float* __restrict__ pospart, const float* __restrict__ negpart,
        float* __restrict__ out) {
    const int t = threadIdx.x;
    const int wave = t >> 6, lane = t & 63;
    float sp = 0.f, sn = 0.f;
    #pragma unroll
    for (int i = 0; i < 4; ++i) {
        sp += pospart[i * 256 + t];
        sn += negpart[i * 256 + t];
    }
    sp = wave_reduce(sp);
    sn = wave_reduce(sn);
    __shared__ float rp[4], rn[4];
    if (lane == 0) { rp[wave] = sp; rn[wave] = sn; }
    __syncthreads();
    if (t == 0) {
        float pos = rp[0] + rp[1] + rp[2] + rp[3];
        float neg = rn[0] + rn[1] + rn[2] + rn[3];
        out[0] = pos * (1.0f / (float)N_ROWS)
               + neg * (1.0f / ((float)N_ROWS * (float)N_ROWS));
    }
}

// ---------------- launch ----------------

extern "C" void kernel_launch(void* const* d_in, const int* in_sizes, int n_in,
                              void* d_out, int out_size, void* d_ws, size_t ws_size,
                              hipStream_t stream) {
    const float* img = (const float*)d_in[0];
    const float* txt = (const float*)d_in[1];
    float* out = (float*)d_out;

    u8* imgn = (u8*)d_ws;                                     // 4 MiB
    u8* txtn = imgn + (size_t)N_ROWS * DIM;                   // 4 MiB
    float* pospart = (float*)(txtn + (size_t)N_ROWS * DIM);   // 4 KiB
    float* negpart = pospart + 1024;                          // 4 KiB

    rowprep<<<N_ROWS / 4, 256, 0, stream>>>(img, txt, imgn, txtn, pospart);
    negloss<<<dim3(N_ROWS / BN, N_ROWS / BM), 256, 0, stream>>>(imgn, txtn, negpart);
    finalize<<<1, 256, 0, stream>>>(pospart, negpart, out);
}